// Round 11
// baseline (237.379 us; speedup 1.0000x reference)
//
#include <hip/hip_runtime.h>

#define BSZ   4
#define TSEQ  4096
#define DEMB  256
#define NTOK  (BSZ * TSEQ)   // 16384
#define HID   512
#define SPLITS 4
#define KEYS_PER_SPLIT (TSEQ / SPLITS)   // 1024
#define TK 32
#define NT (KEYS_PER_SPLIT / TK)         // 32 tiles per split
#define KIMG_STRIDE 8704    // shorts per K tile image  (17408 B = 17 x 1KB DMA)
#define VIMG_STRIDE 10240   // shorts per V^T tile image (20480 B = 20 x 1KB DMA)

using bf16x8 = __attribute__((ext_vector_type(8))) short;
using f32x16 = __attribute__((ext_vector_type(16))) float;

static __device__ __forceinline__ unsigned short f2bf(float f) {
  union { float f; unsigned u; } v; v.f = f;
  unsigned r = v.u + 0x7FFF + ((v.u >> 16) & 1);   // RNE
  return (unsigned short)(r >> 16);
}
static __device__ __forceinline__ float bf2f(unsigned short u) {
  union { unsigned u; float f; } v; v.u = ((unsigned)u) << 16;
  return v.f;
}

// async global->LDS DMA, 16 B/lane: lds dest = uniform base + lane*16
static __device__ __forceinline__ void async16(void* lds, const void* gp) {
  __builtin_amdgcn_global_load_lds(
      (const __attribute__((address_space(1))) unsigned int*)gp,
      (__attribute__((address_space(3))) unsigned int*)lds, 16, 0, 0);
}

// ---------------------------------------------------------------------------
// Prep: y<3 -> qkv [3][K][N] fp32 -> qkvT [3][N][K] bf16 (16 tiles, x<16)
//       y=3/4 -> w1/w2 fp32 -> bf16 cast (x = 0..127)
// ---------------------------------------------------------------------------
__global__ __launch_bounds__(256) void prep_kernel(
    const float* __restrict__ qkv, const float* __restrict__ w1,
    const float* __restrict__ w2, unsigned short* __restrict__ qkvT,
    unsigned short* __restrict__ w1b, unsigned short* __restrict__ w2b)
{
  const int tid = threadIdx.x;
  if (blockIdx.y < 3) {
    if (blockIdx.x >= 16) return;
    __shared__ float Ts[64][65];
    const int z  = blockIdx.y;
    const int k0 = (blockIdx.x >> 2) * 64;
    const int j0 = (blockIdx.x & 3) * 64;
    const float* src = qkv + (size_t)z * DEMB * DEMB + (size_t)k0 * DEMB + j0;
#pragma unroll
    for (int p = 0; p < 4; ++p) {
      int idx = p * 256 + tid;
      int r = idx >> 4, g = idx & 15;
      float4 v = *(const float4*)(src + (size_t)r * DEMB + g * 4);
      Ts[r][g * 4 + 0] = v.x; Ts[r][g * 4 + 1] = v.y;
      Ts[r][g * 4 + 2] = v.z; Ts[r][g * 4 + 3] = v.w;
    }
    __syncthreads();
    unsigned short* dst = qkvT + (size_t)z * DEMB * DEMB + (size_t)j0 * DEMB + k0;
#pragma unroll
    for (int p = 0; p < 4; ++p) {
      int idx = p * 256 + tid;
      int r = idx >> 4, g = idx & 15;
      ushort4 o;
      o.x = f2bf(Ts[g * 4 + 0][r]); o.y = f2bf(Ts[g * 4 + 1][r]);
      o.z = f2bf(Ts[g * 4 + 2][r]); o.w = f2bf(Ts[g * 4 + 3][r]);
      *(ushort4*)(dst + (size_t)r * DEMB + g * 4) = o;
    }
  } else {
    const float* s = (blockIdx.y == 3) ? w1 : w2;
    unsigned short* d = (blockIdx.y == 3) ? w1b : w2b;
    const int i = blockIdx.x * 256 + tid;
    float4 v = ((const float4*)s)[i];
    ushort4 o;
    o.x = f2bf(v.x); o.y = f2bf(v.y); o.z = f2bf(v.z); o.w = f2bf(v.w);
    ((ushort4*)d)[i] = o;
  }
}

// ---------------------------------------------------------------------------
// Fused QKV projection + LN(Q/K) + V-transpose.  128-token x 256-col tiles,
// 256 thr (4 waves, wave w owns rows w*32..+31, all 256 cols), grid
// (NTOK/128, 3) = 384 blocks, 2 blocks/CU.
// V transpose: TWO HALVES of 128 dims at LDS pitch 130 (128x130 = 16640
// shorts fits in sh; single-pass pitch-130 with 256 cols ALIASES — R10 bug).
// ---------------------------------------------------------------------------
__global__ __launch_bounds__(256, 2) void qkvln_kernel(
    const float* __restrict__ x, const unsigned short* __restrict__ qkvT,
    const float* __restrict__ lnqw, const float* __restrict__ lnqb,
    const float* __restrict__ lnkw, const float* __restrict__ lnkb,
    unsigned short* __restrict__ Qbn, unsigned short* __restrict__ Kimg,
    unsigned short* __restrict__ Vimg)
{
  __shared__ __align__(16) unsigned short sh[128 * 72 + 256 * 72];  // 55296 B
  unsigned short* As = sh;             // 128 x 72
  unsigned short* Bs = sh + 128 * 72;  // 256 x 72

  const int tid = threadIdx.x;
  const int w   = tid >> 6;
  const int l   = tid & 63;
  const int lm  = l & 31;
  const int lh  = l >> 5;
  const int z   = blockIdx.y;
  const int m0  = blockIdx.x * 128;
  const int bb  = m0 >> 12;

  const unsigned short* Bt = qkvT + (size_t)z * DEMB * DEMB;

  f32x16 o[8];
#pragma unroll
  for (int t = 0; t < 8; ++t)
#pragma unroll
    for (int r = 0; r < 16; ++r) o[t][r] = 0.f;

  float4 arf[8];
  bf16x8 brb[8];
  // preload k0 = 0: A 128x64 fp32 (8 float4/thr), B 256x64 bf16 (8 bf16x8/thr)
#pragma unroll
  for (int i = 0; i < 8; ++i) {
    const int ia = i * 256 + tid;
    arf[i] = *(const float4*)(x + (size_t)(m0 + (ia >> 4)) * DEMB + (ia & 15) * 4);
    brb[i] = *(const bf16x8*)(Bt + (size_t)(ia >> 3) * DEMB + (ia & 7) * 8);
  }

  for (int k0 = 0; k0 < DEMB; k0 += 64) {
    __syncthreads();
#pragma unroll
    for (int i = 0; i < 8; ++i) {
      const int ia = i * 256 + tid;
      ushort4 u;
      u.x = f2bf(arf[i].x); u.y = f2bf(arf[i].y);
      u.z = f2bf(arf[i].z); u.w = f2bf(arf[i].w);
      *(ushort4*)&As[(ia >> 4) * 72 + (ia & 15) * 4] = u;
      *(bf16x8*)&Bs[(ia >> 3) * 72 + (ia & 7) * 8] = brb[i];
    }
    __syncthreads();

    if (k0 + 64 < DEMB) {
      const int kn = k0 + 64;
#pragma unroll
      for (int i = 0; i < 8; ++i) {
        const int ia = i * 256 + tid;
        arf[i] = *(const float4*)(x + (size_t)(m0 + (ia >> 4)) * DEMB + kn + (ia & 15) * 4);
        brb[i] = *(const bf16x8*)(Bt + (size_t)(ia >> 3) * DEMB + kn + (ia & 7) * 8);
      }
    }

#pragma unroll
    for (int ks = 0; ks < 4; ++ks) {
      bf16x8 a = *(const bf16x8*)&As[(w * 32 + lm) * 72 + ks * 16 + lh * 8];
#pragma unroll
      for (int t = 0; t < 8; ++t) {
        bf16x8 b = *(const bf16x8*)&Bs[(t * 32 + lm) * 72 + ks * 16 + lh * 8];
        o[t] = __builtin_amdgcn_mfma_f32_32x32x16_bf16(a, b, o[t], 0, 0, 0);
      }
    }
  }

  if (z < 2) {
    // ---- LayerNorm in-register (rows lane-private), write Qbn / Kimg ----
    const float* wp = z ? lnkw : lnqw;
    const float* bp = z ? lnkb : lnqb;
    float wc[8], bc[8];
#pragma unroll
    for (int t = 0; t < 8; ++t) { wc[t] = wp[t * 32 + lm]; bc[t] = bp[t * 32 + lm]; }
#pragma unroll
    for (int r = 0; r < 16; ++r) {
      float sv = 0.f, sq = 0.f;
#pragma unroll
      for (int t = 0; t < 8; ++t) { const float v = o[t][r]; sv += v; sq += v * v; }
#pragma unroll
      for (int d = 1; d < 32; d <<= 1) { sv += __shfl_xor(sv, d, 64); sq += __shfl_xor(sq, d, 64); }
      const float mean = sv * (1.f / DEMB);
      const float rs = rsqrtf(sq * (1.f / DEMB) - mean * mean + 1e-5f);
      const int token = m0 + w * 32 + (r & 3) + 8 * (r >> 2) + 4 * lh;
      if (z == 0) {
        unsigned short* dst = Qbn + (size_t)token * DEMB;
#pragma unroll
        for (int t = 0; t < 8; ++t)
          dst[t * 32 + lm] = f2bf((o[t][r] - mean) * rs * wc[t] + bc[t]);
      } else {
        const int t5 = token & 4095;
        unsigned short* dst =
            Kimg + (size_t)(bb * 128 + (t5 >> 5)) * KIMG_STRIDE + (t5 & 31) * 264;
#pragma unroll
        for (int t = 0; t < 8; ++t)
          dst[t * 32 + lm] = f2bf((o[t][r] - mean) * rs * wc[t] + bc[t]);
      }
    }
  } else {
    // ---- V: transpose via LDS, two 128-dim halves at pitch 130 ----
#pragma unroll
    for (int h = 0; h < 2; ++h) {
      __syncthreads();   // h=0: frag reads done; h=1: prior half's reads done
#pragma unroll
      for (int t2 = 0; t2 < 4; ++t2) {
        const int t = h * 4 + t2;
#pragma unroll
        for (int r = 0; r < 16; ++r) {
          const int row = w * 32 + (r & 3) + 8 * (r >> 2) + 4 * lh;
          sh[row * 130 + t2 * 32 + lm] = f2bf(o[t][r]);
        }
      }
      __syncthreads();
      const int d2 = tid & 127;          // local dim within half
      const int tq = tid >> 7;           // 0..1: tokens tq*64..+63
      const int d  = h * 128 + d2;
#pragma unroll
      for (int j = 0; j < 16; ++j) {
        const int tok0 = tq * 64 + j * 4;
        ushort4 v;
        v.x = sh[(tok0 + 0) * 130 + d2];
        v.y = sh[(tok0 + 1) * 130 + d2];
        v.z = sh[(tok0 + 2) * 130 + d2];
        v.w = sh[(tok0 + 3) * 130 + d2];
        const int gtok = m0 + tok0;
        const int kt = (gtok & 4095) >> 5;
        *(ushort4*)(Vimg + (size_t)(bb * 128 + kt) * VIMG_STRIDE + d * 40 + (tok0 & 31)) = v;
      }
    }
  }
}

// ---------------------------------------------------------------------------
// Fused FFN: out = 0.7*(x1 + LN(leaky(leaky(x1b @ w1^T) @ w2^T))).
// 64-token tiles, 256 blocks (1/CU), 256 thr (4 waves).
// Phase 1: H[64][512] = leaky(x1b @ w1^T) -> LDS (pitch 520, never HBM).
// Phase 2: Y2[64][256] = leaky(H @ w2^T); wave w owns cols w*64..+63 (2x2).
// Epilogue: cross-wave LN row stats via LDS scratch, residual RMW on Out.
// LDS: As 9216 + Bs 73728 + Hs 66560 = 149504 B -> 1 block/CU.
// ---------------------------------------------------------------------------
__global__ __launch_bounds__(256, 1) void ffn_fused_kernel(
    const unsigned short* __restrict__ x1b, const unsigned short* __restrict__ w1b,
    const unsigned short* __restrict__ w2b, const float* __restrict__ lnw,
    const float* __restrict__ lnb, float* __restrict__ Out)
{
  __shared__ __align__(16) unsigned short As[64 * 72];
  __shared__ __align__(16) unsigned short Bs[512 * 72];
  __shared__ __align__(16) unsigned short Hs[64 * 520];

  const int tid = threadIdx.x;
  const int w   = tid >> 6;
  const int l   = tid & 63;
  const int lm  = l & 31;
  const int lh  = l >> 5;
  const int m0  = blockIdx.x * 64;

  // ---------------- phase 1: H = leaky(x1b @ w1^T) ----------------
  f32x16 a1[8];   // [c*2+rt]
#pragma unroll
  for (int i = 0; i < 8; ++i)
#pragma unroll
    for (int r = 0; r < 16; ++r) a1[i][r] = 0.f;

  bf16x8 ar[2], br[16];
#pragma unroll
  for (int i = 0; i < 2; ++i) {
    const int ia = i * 256 + tid;
    ar[i] = *(const bf16x8*)(x1b + (size_t)(m0 + (ia >> 3)) * DEMB + (ia & 7) * 8);
  }
#pragma unroll
  for (int i = 0; i < 16; ++i) {
    const int ia = i * 256 + tid;
    br[i] = *(const bf16x8*)(w1b + (size_t)(ia >> 3) * DEMB + (ia & 7) * 8);
  }

  for (int kc = 0; kc < 4; ++kc) {
    __syncthreads();
#pragma unroll
    for (int i = 0; i < 2; ++i) {
      const int ia = i * 256 + tid;
      *(bf16x8*)&As[(ia >> 3) * 72 + (ia & 7) * 8] = ar[i];
    }
#pragma unroll
    for (int i = 0; i < 16; ++i) {
      const int ia = i * 256 + tid;
      *(bf16x8*)&Bs[(ia >> 3) * 72 + (ia & 7) * 8] = br[i];
    }
    __syncthreads();

    if (kc < 3) {
      const int kn = (kc + 1) * 64;
#pragma unroll
      for (int i = 0; i < 2; ++i) {
        const int ia = i * 256 + tid;
        ar[i] = *(const bf16x8*)(x1b + (size_t)(m0 + (ia >> 3)) * DEMB + kn + (ia & 7) * 8);
      }
#pragma unroll
      for (int i = 0; i < 16; ++i) {
        const int ia = i * 256 + tid;
        br[i] = *(const bf16x8*)(w1b + (size_t)(ia >> 3) * DEMB + kn + (ia & 7) * 8);
      }
    }

#pragma unroll
    for (int ks = 0; ks < 4; ++ks) {
      bf16x8 a0  = *(const bf16x8*)&As[lm * 72 + ks * 16 + lh * 8];
      bf16x8 a1f = *(const bf16x8*)&As[(32 + lm) * 72 + ks * 16 + lh * 8];
#pragma unroll
      for (int c = 0; c < 4; ++c) {
        bf16x8 b = *(const bf16x8*)&Bs[(w * 128 + c * 32 + lm) * 72 + ks * 16 + lh * 8];
        a1[c * 2 + 0] = __builtin_amdgcn_mfma_f32_32x32x16_bf16(a0,  b, a1[c * 2 + 0], 0, 0, 0);
        a1[c * 2 + 1] = __builtin_amdgcn_mfma_f32_32x32x16_bf16(a1f, b, a1[c * 2 + 1], 0, 0, 0);
      }
    }
  }

  // leaky + dump H to LDS (row-major, pitch 520)
#pragma unroll
  for (int c = 0; c < 4; ++c)
#pragma unroll
    for (int rt = 0; rt < 2; ++rt)
#pragma unroll
      for (int r = 0; r < 16; ++r) {
        const int row = rt * 32 + (r & 3) + 8 * (r >> 2) + 4 * lh;
        const int col = w * 128 + c * 32 + lm;
        float v = a1[c * 2 + rt][r];
        v = v > 0.f ? v : 0.2f * v;
        Hs[row * 520 + col] = f2bf(v);
      }

  // ---------------- phase 2: Y2 = leaky(H @ w2^T) ----------------
  f32x16 a2[4];   // [ct*2+rt]; cols w*64+ct*32, rows rt*32
#pragma unroll
  for (int i = 0; i < 4; ++i)
#pragma unroll
    for (int r = 0; r < 16; ++r) a2[i][r] = 0.f;

  bf16x8 wr[8];
#pragma unroll
  for (int i = 0; i < 8; ++i) {
    const int ia = i * 256 + tid;
    wr[i] = *(const bf16x8*)(w2b + (size_t)(ia >> 3) * HID + (ia & 7) * 8);
  }

  for (int kc = 0; kc < 8; ++kc) {
    __syncthreads();   // (first iter: also covers H dump visibility)
#pragma unroll
    for (int i = 0; i < 8; ++i) {
      const int ia = i * 256 + tid;
      *(bf16x8*)&Bs[(ia >> 3) * 72 + (ia & 7) * 8] = wr[i];
    }
    __syncthreads();

    if (kc < 7) {
      const int kn = (kc + 1) * 64;
#pragma unroll
      for (int i = 0; i < 8; ++i) {
        const int ia = i * 256 + tid;
        wr[i] = *(const bf16x8*)(w2b + (size_t)(ia >> 3) * HID + kn + (ia & 7) * 8);
      }
    }

#pragma unroll
    for (int ks = 0; ks < 4; ++ks) {
      const int kk = kc * 64 + ks * 16 + lh * 8;
      bf16x8 h0 = *(const bf16x8*)&Hs[lm * 520 + kk];
      bf16x8 h1 = *(const bf16x8*)&Hs[(32 + lm) * 520 + kk];
      bf16x8 b0 = *(const bf16x8*)&Bs[(w * 64 + lm) * 72 + ks * 16 + lh * 8];
      bf16x8 b1 = *(const bf16x8*)&Bs[(w * 64 + 32 + lm) * 72 + ks * 16 + lh * 8];
      a2[0] = __builtin_amdgcn_mfma_f32_32x32x16_bf16(h0, b0, a2[0], 0, 0, 0);
      a2[1] = __builtin_amdgcn_mfma_f32_32x32x16_bf16(h1, b0, a2[1], 0, 0, 0);
      a2[2] = __builtin_amdgcn_mfma_f32_32x32x16_bf16(h0, b1, a2[2], 0, 0, 0);
      a2[3] = __builtin_amdgcn_mfma_f32_32x32x16_bf16(h1, b1, a2[3], 0, 0, 0);
    }
  }

  // ---------------- epilogue: leaky + LN + residual ----------------
  float* Sst = (float*)As;   // [wave][row][2] = 4*64*2 floats = 2 KB
#pragma unroll
  for (int rt = 0; rt < 2; ++rt)
#pragma unroll
    for (int r = 0; r < 16; ++r) {
      float y0 = a2[rt][r];      y0 = y0 > 0.f ? y0 : 0.2f * y0;
      float y1 = a2[2 + rt][r];  y1 = y1 > 0.f ? y1 : 0.2f * y1;
      a2[rt][r] = y0; a2[2 + rt][r] = y1;
      float sv = y0 + y1, sq = y0 * y0 + y1 * y1;
#pragma unroll
      for (int d = 1; d < 32; d <<= 1) { sv += __shfl_xor(sv, d, 64); sq += __shfl_xor(sq, d, 64); }
      const int row = rt * 32 + (r & 3) + 8 * (r >> 2) + 4 * lh;
      if (lm == 0) { Sst[(w * 64 + row) * 2] = sv; Sst[(w * 64 + row) * 2 + 1] = sq; }
    }
  __syncthreads();
  float lw[2], lb[2];
#pragma unroll
  for (int ct = 0; ct < 2; ++ct) {
    lw[ct] = lnw[w * 64 + ct * 32 + lm];
    lb[ct] = lnb[w * 64 + ct * 32 + lm];
  }
#pragma unroll
  for (int rt = 0; rt < 2; ++rt)
#pragma unroll
    for (int r = 0; r < 16; ++r) {
      const int row = rt * 32 + (r & 3) + 8 * (r >> 2) + 4 * lh;
      float sv = Sst[row * 2] + Sst[(64 + row) * 2] + Sst[(128 + row) * 2] + Sst[(192 + row) * 2];
      float sq = Sst[row * 2 + 1] + Sst[(64 + row) * 2 + 1] + Sst[(128 + row) * 2 + 1] + Sst[(192 + row) * 2 + 1];
      const float mean = sv * (1.f / DEMB);
      const float rs = rsqrtf(sq * (1.f / DEMB) - mean * mean + 1e-5f);
#pragma unroll
      for (int ct = 0; ct < 2; ++ct) {
        const int col = w * 64 + ct * 32 + lm;
        const float val = (a2[ct * 2 + rt][r] - mean) * rs * lw[ct] + lb[ct];
        const size_t g = (size_t)(m0 + row) * DEMB + col;
        Out[g] = 0.7f * (Out[g] + val);   // Out holds x1; same-thread RMW safe
      }
    }
}

// ---------------------------------------------------------------------------
// Split-K MFMA flash attention (unchanged from R8): fixed-offset softmax,
// 512 thr, one barrier/iter, PV lags QK by one tile, K dbuf + V tbuf DMA.
// ---------------------------------------------------------------------------
__global__ __launch_bounds__(512) void attn_split_kernel(
    const unsigned short* __restrict__ Qb, const unsigned short* __restrict__ Kimg,
    const unsigned short* __restrict__ Vimg, unsigned short* __restrict__ Opart,
    float* __restrict__ lpart)
{
  __shared__ __align__(16) unsigned short Ks[2][KIMG_STRIDE];
  __shared__ __align__(16) unsigned short Vs[3][VIMG_STRIDE];
  __shared__ __align__(16) unsigned short Pb[8 * 32 * 40];

  const int tid = threadIdx.x;
  const int w   = tid >> 6;
  const int l   = tid & 63;
  const int lm  = l & 31;
  const int lh  = l >> 5;

  const int lin = blockIdx.x;
  const int xcd = lin & 7;
  const int idx = lin >> 3;
  const int b     = xcd >> 1;
  const int split = (xcd & 1) * 2 + (idx & 1);
  const int q0    = (idx >> 1) * 256;

  const unsigned short* Qbase  = Qb + (size_t)b * TSEQ * DEMB;
  const unsigned short* Ktiles = Kimg + (size_t)(b * 128 + split * 32) * KIMG_STRIDE;
  const unsigned short* Vtiles = Vimg + (size_t)(b * 128 + split * 32) * VIMG_STRIDE;

  bf16x8 qf[16];
  {
    const unsigned short* qrow = Qbase + (size_t)(q0 + w * 32 + lm) * DEMB + lh * 8;
#pragma unroll
    for (int ks = 0; ks < 16; ++ks) qf[ks] = *(const bf16x8*)(qrow + ks * 16);
  }

  f32x16 o[8];
  float lsum[16], spv[16];
#pragma unroll
  for (int t = 0; t < 8; ++t)
#pragma unroll
    for (int r = 0; r < 16; ++r) o[t][r] = 0.f;
#pragma unroll
  for (int r = 0; r < 16; ++r) lsum[r] = 0.f;

  unsigned short* Pw = &Pb[w * 32 * 40];

#pragma unroll
  for (int i = 0; i < 3; ++i) {
    const int c = w + 8 * i;
    if (c < 17) async16(&Ks[0][c * 512], Ktiles + c * 512 + l * 8);
  }
#pragma unroll
  for (int i = 0; i < 3; ++i) {
    const int c = w + 8 * i;
    if (c < 20) async16(&Vs[0][c * 512], Vtiles + c * 512 + l * 8);
  }

  {
    __syncthreads();
#pragma unroll
    for (int i = 0; i < 3; ++i) {
      const int c = w + 8 * i;
      if (c < 17) async16(&Ks[1][c * 512], Ktiles + (size_t)KIMG_STRIDE + c * 512 + l * 8);
    }
#pragma unroll
    for (int i = 0; i < 3; ++i) {
      const int c = w + 8 * i;
      if (c < 20) async16(&Vs[1][c * 512], Vtiles + (size_t)VIMG_STRIDE + c * 512 + l * 8);
    }
    f32x16 s;
#pragma unroll
    for (int r = 0; r < 16; ++r) s[r] = 0.f;
#pragma unroll
    for (int ks = 0; ks < 16; ++ks) {
      bf16x8 kf = *(const bf16x8*)&Ks[0][lm * 264 + ks * 16 + lh * 8];
      s = __builtin_amdgcn_mfma_f32_32x32x16_bf16(qf[ks], kf, s, 0, 0, 0);
    }
#pragma unroll
    for (int r = 0; r < 16; ++r) spv[r] = s[r];
  }

  int vprev = 0, vcur = 1, vnext = 2;

  for (int st = 1; st < NT; ++st) {
    __syncthreads();

    if (st + 1 < NT) {
      const unsigned short* kn = Ktiles + (size_t)(st + 1) * KIMG_STRIDE;
      const unsigned short* vn = Vtiles + (size_t)(st + 1) * VIMG_STRIDE;
#pragma unroll
      for (int i = 0; i < 3; ++i) {
        const int c = w + 8 * i;
        if (c < 17) async16(&Ks[(st + 1) & 1][c * 512], kn + c * 512 + l * 8);
      }
#pragma unroll
      for (int i = 0; i < 3; ++i) {
        const int c = w + 8 * i;
        if (c < 20) async16(&Vs[vnext][c * 512], vn + c * 512 + l * 8);
      }
    }

#pragma unroll
    for (int r = 0; r < 16; ++r) {
      const float pv = exp2f(spv[r] * 0.09016844335f - 11.541560327f);
      lsum[r] += pv;
      const int row = (r & 3) + ((r >> 2) << 3) + (lh << 2);
      Pw[row * 40 + lm] = f2bf(pv);
    }
    {
      const unsigned short* Vp = &Vs[vprev][0];
#pragma unroll
      for (int ks = 0; ks < 2; ++ks) {
        bf16x8 pf = *(const bf16x8*)&Pw[lm * 40 + ks * 16 + lh * 8];
#pragma unroll
        for (int t = 0; t < 8; ++t) {
          bf16x8 vf = *(const bf16x8*)&Vp[(t * 32 + lm) * 40 + ks * 16 + lh * 8];
          o[t] = __builtin_amdgcn_mfma_f32_32x32x16_bf16(pf, vf, o[t], 0, 0, 0);
        }
      }
    }

    {
      f32x16 s;
#pragma unroll
      for (int r = 0; r < 16; ++r) s[r] = 0.f;
      const unsigned short* Kp = &Ks[st & 1][0];
#pragma unroll
      for (int ks = 0; ks < 16; ++ks) {
        bf16x8 kf = *(const bf16x8*)&Kp[lm * 264 + ks * 16 + lh * 8];
        s = __builtin_amdgcn_mfma_f32_32x32x16_bf16(qf[ks], kf, s, 0, 0, 0);
      }
#pragma unroll
      for (int r = 0; r < 16; ++r) spv[r] = s[r];
    }

    const int tmp = vprev; vprev = vcur; vcur = vnext; vnext = tmp;
  }

#pragma unroll
  for (int r = 0; r < 16; ++r) {
    const float pv = exp2f(spv[r] * 0.09016844335f - 11.541560327f);
    lsum[r] += pv;
    const int row = (r & 3) + ((r >> 2) << 3) + (lh << 2);
    Pw[row * 40 + lm] = f2bf(pv);
  }
  {
    const unsigned short* Vp = &Vs[vprev][0];
#pragma unroll
    for (int ks = 0; ks < 2; ++ks) {
      bf16x8 pf = *(const bf16x8*)&Pw[lm * 40 + ks * 16 + lh * 8];
#pragma unroll
      for (int t = 0; t < 8; ++t) {
        bf16x8 vf = *(const bf16x8*)&Vp[(t * 32 + lm) * 40 + ks * 16 + lh * 8];
        o[t] = __builtin_amdgcn_mfma_f32_32x32x16_bf16(pf, vf, o[t], 0, 0, 0);
      }
    }
  }

#pragma unroll
  for (int r = 0; r < 16; ++r) {
#pragma unroll
    for (int d = 1; d < 32; d <<= 1) lsum[r] += __shfl_xor(lsum[r], d, 64);
  }
  unsigned short* Ob =
      Opart + ((size_t)split * NTOK + (size_t)b * TSEQ + q0 + w * 32) * DEMB;
  float* lb = lpart + (size_t)split * NTOK + (size_t)b * TSEQ + q0 + w * 32;
#pragma unroll
  for (int r = 0; r < 16; ++r) {
    const int row = (r & 3) + ((r >> 2) << 3) + (lh << 2);
#pragma unroll
    for (int t = 0; t < 8; ++t)
      Ob[(size_t)row * DEMB + t * 32 + lm] = f2bf(o[t][r]);
    if (lm == 0) lb[row] = lsum[r];
  }
}

// ---------------------------------------------------------------------------
// Combine partials + attn LayerNorm + residual; emits fp32 x1 and bf16 copy.
// ---------------------------------------------------------------------------
__global__ __launch_bounds__(256) void combine_lnres_kernel(
    const unsigned short* __restrict__ Opart, const float* __restrict__ lpart,
    const float* __restrict__ Xin, const float* __restrict__ w,
    const float* __restrict__ b, float* __restrict__ Out,
    unsigned short* __restrict__ Outb)
{
  const int lane = threadIdx.x & 63;
  const size_t row = (size_t)blockIdx.x * 4 + (threadIdx.x >> 6);
  float4 acc = make_float4(0.f, 0.f, 0.f, 0.f);
  float lt = 0.f;
#pragma unroll
  for (int p = 0; p < SPLITS; ++p) {
    const ushort4 u = *(const ushort4*)&Opart[((size_t)p * NTOK + row) * DEMB + lane * 4];
    acc.x += bf2f(u.x); acc.y += bf2f(u.y);
    acc.z += bf2f(u.z); acc.w += bf2f(u.w);
    lt += lpart[(size_t)p * NTOK + row];
  }
  const float inv = 1.f / lt;
  const float y0 = acc.x * inv, y1 = acc.y * inv, y2 = acc.z * inv, y3 = acc.w * inv;
  float s  = y0 + y1 + y2 + y3;
  float sq = y0 * y0 + y1 * y1 + y2 * y2 + y3 * y3;
#pragma unroll
  for (int o = 32; o > 0; o >>= 1) { s += __shfl_down(s, o); sq += __shfl_down(sq, o); }
  s = __shfl(s, 0); sq = __shfl(sq, 0);
  const float m  = s * (1.f / DEMB);
  const float rs = rsqrtf(sq * (1.f / DEMB) - m * m + 1e-5f);
  const float4 wv = *(const float4*)&w[lane * 4];
  const float4 bv = *(const float4*)&b[lane * 4];
  const float4 xi = *(const float4*)&Xin[row * DEMB + lane * 4];
  float4 o;
  o.x = 0.7f * (xi.x + (y0 - m) * rs * wv.x + bv.x);
  o.y = 0.7f * (xi.y + (y1 - m) * rs * wv.y + bv.y);
  o.z = 0.7f * (xi.z + (y2 - m) * rs * wv.z + bv.z);
  o.w = 0.7f * (xi.w + (y3 - m) * rs * wv.w + bv.w);
  *(float4*)&Out[row * DEMB + lane * 4] = o;
  ushort4 ob;
  ob.x = f2bf(o.x); ob.y = f2bf(o.y); ob.z = f2bf(o.z); ob.w = f2bf(o.w);
  *(ushort4*)&Outb[row * DEMB + lane * 4] = ob;
}

// ---------------------------------------------------------------------------
extern "C" void kernel_launch(void* const* d_in, const int* in_sizes, int n_in,
                              void* d_out, int out_size, void* d_ws, size_t ws_size,
                              hipStream_t stream)
{
  (void)in_sizes; (void)n_in; (void)out_size; (void)ws_size;
  const float* x    = (const float*)d_in[0];
  const float* qkv  = (const float*)d_in[1];
  const float* lnqw = (const float*)d_in[2];
  const float* lnqb = (const float*)d_in[3];
  const float* lnkw = (const float*)d_in[4];
  const float* lnkb = (const float*)d_in[5];
  const float* lnaw = (const float*)d_in[6];
  const float* lnab = (const float*)d_in[7];
  const float* w1   = (const float*)d_in[8];
  const float* w2   = (const float*)d_in[9];
  const float* lnfw = (const float*)d_in[10];
  const float* lnfb = (const float*)d_in[11];
  float* out = (float*)d_out;

  // byte-offset workspace (lifetimes disjoint):
  //   Qbn[0,8) Kimg[8,17) Vimg[17,28) Opart[28,60) lpart@60
  //   x1b[0,8) (Qbn dead after attn)   qkvT@60.5 w1b@61 w2b@61.25
  char* W = (char*)d_ws;
  const size_t MB = 1 << 20;
  unsigned short* Qbn   = (unsigned short*)(W + 0);
  unsigned short* Kimg  = (unsigned short*)(W + 8 * MB);    // 8.9 MB
  unsigned short* Vimg  = (unsigned short*)(W + 17 * MB);   // 10.5 MB
  unsigned short* Opart = (unsigned short*)(W + 28 * MB);   // 32 MB
  float*          lpart = (float*)(W + 60 * MB);            // 256 KB
  unsigned short* x1b   = (unsigned short*)(W + 0);
  unsigned short* qkvT  = (unsigned short*)(W + 60 * MB + 512 * 1024);  // 384 KB
  unsigned short* w1b   = (unsigned short*)(W + 61 * MB);               // 256 KB
  unsigned short* w2b   = (unsigned short*)(W + 61 * MB + 256 * 1024);  // 256 KB

  const dim3 blk(256);

  // weight prep: qkv transpose+cast + w1/w2 cast
  prep_kernel<<<dim3(128, 5), blk, 0, stream>>>(qkv, w1, w2, qkvT, w1b, w2b);

  // fused QKV projection + LN(Q/K) + V-transpose (384 blocks, 2/CU)
  qkvln_kernel<<<dim3(NTOK / 128, 3), blk, 0, stream>>>(
      x, qkvT, lnqw, lnqb, lnkw, lnkb, Qbn, Kimg, Vimg);

  // attention (split-K, PV-lags-QK pipeline) + fused combine/LN/residual
  attn_split_kernel<<<dim3(256), dim3(512), 0, stream>>>(Qbn, Kimg, Vimg, Opart, lpart);
  combine_lnres_kernel<<<NTOK / 4, blk, 0, stream>>>(Opart, lpart, x, lnaw, lnab, out, x1b);

  // fused FFN1+FFN2+final-LN (H lives in LDS; out updated in place)
  ffn_fused_kernel<<<dim3(NTOK / 64), blk, 0, stream>>>(
      x1b, w1b, w2b, lnfw, lnfb, out);
}

// Round 12
// 229.487 us; speedup vs baseline: 1.0344x; 1.0344x over previous
//
#include <hip/hip_runtime.h>

#define BSZ   4
#define TSEQ  4096
#define DEMB  256
#define NTOK  (BSZ * TSEQ)   // 16384
#define HID   512
#define SPLITS 4
#define KEYS_PER_SPLIT (TSEQ / SPLITS)   // 1024
#define TK 32
#define NT (KEYS_PER_SPLIT / TK)         // 32 tiles per split
#define KIMG_STRIDE 8704    // shorts per K tile image  (17408 B = 17 x 1KB DMA)
#define VIMG_STRIDE 10240   // shorts per V^T tile image (20480 B = 20 x 1KB DMA)

using bf16x8 = __attribute__((ext_vector_type(8))) short;
using f32x16 = __attribute__((ext_vector_type(16))) float;

static __device__ __forceinline__ unsigned short f2bf(float f) {
  union { float f; unsigned u; } v; v.f = f;
  unsigned r = v.u + 0x7FFF + ((v.u >> 16) & 1);   // RNE
  return (unsigned short)(r >> 16);
}
static __device__ __forceinline__ float bf2f(unsigned short u) {
  union { unsigned u; float f; } v; v.u = ((unsigned)u) << 16;
  return v.f;
}

// async global->LDS DMA, 16 B/lane: lds dest = uniform base + lane*16
static __device__ __forceinline__ void async16(void* lds, const void* gp) {
  __builtin_amdgcn_global_load_lds(
      (const __attribute__((address_space(1))) unsigned int*)gp,
      (__attribute__((address_space(3))) unsigned int*)lds, 16, 0, 0);
}

// ---------------------------------------------------------------------------
// Prep: y<3 -> qkv [3][K][N] fp32 -> qkvT [3][N][K] bf16 (16 tiles, x<16)
//       y=3/4 -> w1/w2 fp32 -> bf16 cast (x = 0..127)
// ---------------------------------------------------------------------------
__global__ __launch_bounds__(256) void prep_kernel(
    const float* __restrict__ qkv, const float* __restrict__ w1,
    const float* __restrict__ w2, unsigned short* __restrict__ qkvT,
    unsigned short* __restrict__ w1b, unsigned short* __restrict__ w2b)
{
  const int tid = threadIdx.x;
  if (blockIdx.y < 3) {
    if (blockIdx.x >= 16) return;
    __shared__ float Ts[64][65];
    const int z  = blockIdx.y;
    const int k0 = (blockIdx.x >> 2) * 64;
    const int j0 = (blockIdx.x & 3) * 64;
    const float* src = qkv + (size_t)z * DEMB * DEMB + (size_t)k0 * DEMB + j0;
#pragma unroll
    for (int p = 0; p < 4; ++p) {
      int idx = p * 256 + tid;
      int r = idx >> 4, g = idx & 15;
      float4 v = *(const float4*)(src + (size_t)r * DEMB + g * 4);
      Ts[r][g * 4 + 0] = v.x; Ts[r][g * 4 + 1] = v.y;
      Ts[r][g * 4 + 2] = v.z; Ts[r][g * 4 + 3] = v.w;
    }
    __syncthreads();
    unsigned short* dst = qkvT + (size_t)z * DEMB * DEMB + (size_t)j0 * DEMB + k0;
#pragma unroll
    for (int p = 0; p < 4; ++p) {
      int idx = p * 256 + tid;
      int r = idx >> 4, g = idx & 15;
      ushort4 o;
      o.x = f2bf(Ts[g * 4 + 0][r]); o.y = f2bf(Ts[g * 4 + 1][r]);
      o.z = f2bf(Ts[g * 4 + 2][r]); o.w = f2bf(Ts[g * 4 + 3][r]);
      *(ushort4*)(dst + (size_t)r * DEMB + g * 4) = o;
    }
  } else {
    const float* s = (blockIdx.y == 3) ? w1 : w2;
    unsigned short* d = (blockIdx.y == 3) ? w1b : w2b;
    const int i = blockIdx.x * 256 + tid;
    float4 v = ((const float4*)s)[i];
    ushort4 o;
    o.x = f2bf(v.x); o.y = f2bf(v.y); o.z = f2bf(v.z); o.w = f2bf(v.w);
    ((ushort4*)d)[i] = o;
  }
}

// ---------------------------------------------------------------------------
// Fused QKV projection + LN(Q/K) + V-transpose (R11, verified correct).
// 128-token x 256-col tiles, 256 thr (4 waves), grid (NTOK/128, 3), 2 blk/CU.
// V transpose: two 128-dim halves at LDS pitch 130 (single-pass aliases).
// ---------------------------------------------------------------------------
__global__ __launch_bounds__(256, 2) void qkvln_kernel(
    const float* __restrict__ x, const unsigned short* __restrict__ qkvT,
    const float* __restrict__ lnqw, const float* __restrict__ lnqb,
    const float* __restrict__ lnkw, const float* __restrict__ lnkb,
    unsigned short* __restrict__ Qbn, unsigned short* __restrict__ Kimg,
    unsigned short* __restrict__ Vimg)
{
  __shared__ __align__(16) unsigned short sh[128 * 72 + 256 * 72];  // 55296 B
  unsigned short* As = sh;             // 128 x 72
  unsigned short* Bs = sh + 128 * 72;  // 256 x 72

  const int tid = threadIdx.x;
  const int w   = tid >> 6;
  const int l   = tid & 63;
  const int lm  = l & 31;
  const int lh  = l >> 5;
  const int z   = blockIdx.y;
  const int m0  = blockIdx.x * 128;
  const int bb  = m0 >> 12;

  const unsigned short* Bt = qkvT + (size_t)z * DEMB * DEMB;

  f32x16 o[8];
#pragma unroll
  for (int t = 0; t < 8; ++t)
#pragma unroll
    for (int r = 0; r < 16; ++r) o[t][r] = 0.f;

  float4 arf[8];
  bf16x8 brb[8];
#pragma unroll
  for (int i = 0; i < 8; ++i) {
    const int ia = i * 256 + tid;
    arf[i] = *(const float4*)(x + (size_t)(m0 + (ia >> 4)) * DEMB + (ia & 15) * 4);
    brb[i] = *(const bf16x8*)(Bt + (size_t)(ia >> 3) * DEMB + (ia & 7) * 8);
  }

  for (int k0 = 0; k0 < DEMB; k0 += 64) {
    __syncthreads();
#pragma unroll
    for (int i = 0; i < 8; ++i) {
      const int ia = i * 256 + tid;
      ushort4 u;
      u.x = f2bf(arf[i].x); u.y = f2bf(arf[i].y);
      u.z = f2bf(arf[i].z); u.w = f2bf(arf[i].w);
      *(ushort4*)&As[(ia >> 4) * 72 + (ia & 15) * 4] = u;
      *(bf16x8*)&Bs[(ia >> 3) * 72 + (ia & 7) * 8] = brb[i];
    }
    __syncthreads();

    if (k0 + 64 < DEMB) {
      const int kn = k0 + 64;
#pragma unroll
      for (int i = 0; i < 8; ++i) {
        const int ia = i * 256 + tid;
        arf[i] = *(const float4*)(x + (size_t)(m0 + (ia >> 4)) * DEMB + kn + (ia & 15) * 4);
        brb[i] = *(const bf16x8*)(Bt + (size_t)(ia >> 3) * DEMB + kn + (ia & 7) * 8);
      }
    }

#pragma unroll
    for (int ks = 0; ks < 4; ++ks) {
      bf16x8 a = *(const bf16x8*)&As[(w * 32 + lm) * 72 + ks * 16 + lh * 8];
#pragma unroll
      for (int t = 0; t < 8; ++t) {
        bf16x8 b = *(const bf16x8*)&Bs[(t * 32 + lm) * 72 + ks * 16 + lh * 8];
        o[t] = __builtin_amdgcn_mfma_f32_32x32x16_bf16(a, b, o[t], 0, 0, 0);
      }
    }
  }

  if (z < 2) {
    const float* wp = z ? lnkw : lnqw;
    const float* bp = z ? lnkb : lnqb;
    float wc[8], bc[8];
#pragma unroll
    for (int t = 0; t < 8; ++t) { wc[t] = wp[t * 32 + lm]; bc[t] = bp[t * 32 + lm]; }
#pragma unroll
    for (int r = 0; r < 16; ++r) {
      float sv = 0.f, sq = 0.f;
#pragma unroll
      for (int t = 0; t < 8; ++t) { const float v = o[t][r]; sv += v; sq += v * v; }
#pragma unroll
      for (int d = 1; d < 32; d <<= 1) { sv += __shfl_xor(sv, d, 64); sq += __shfl_xor(sq, d, 64); }
      const float mean = sv * (1.f / DEMB);
      const float rs = rsqrtf(sq * (1.f / DEMB) - mean * mean + 1e-5f);
      const int token = m0 + w * 32 + (r & 3) + 8 * (r >> 2) + 4 * lh;
      if (z == 0) {
        unsigned short* dst = Qbn + (size_t)token * DEMB;
#pragma unroll
        for (int t = 0; t < 8; ++t)
          dst[t * 32 + lm] = f2bf((o[t][r] - mean) * rs * wc[t] + bc[t]);
      } else {
        const int t5 = token & 4095;
        unsigned short* dst =
            Kimg + (size_t)(bb * 128 + (t5 >> 5)) * KIMG_STRIDE + (t5 & 31) * 264;
#pragma unroll
        for (int t = 0; t < 8; ++t)
          dst[t * 32 + lm] = f2bf((o[t][r] - mean) * rs * wc[t] + bc[t]);
      }
    }
  } else {
#pragma unroll
    for (int h = 0; h < 2; ++h) {
      __syncthreads();
#pragma unroll
      for (int t2 = 0; t2 < 4; ++t2) {
        const int t = h * 4 + t2;
#pragma unroll
        for (int r = 0; r < 16; ++r) {
          const int row = w * 32 + (r & 3) + 8 * (r >> 2) + 4 * lh;
          sh[row * 130 + t2 * 32 + lm] = f2bf(o[t][r]);
        }
      }
      __syncthreads();
      const int d2 = tid & 127;
      const int tq = tid >> 7;
      const int d  = h * 128 + d2;
#pragma unroll
      for (int j = 0; j < 16; ++j) {
        const int tok0 = tq * 64 + j * 4;
        ushort4 v;
        v.x = sh[(tok0 + 0) * 130 + d2];
        v.y = sh[(tok0 + 1) * 130 + d2];
        v.z = sh[(tok0 + 2) * 130 + d2];
        v.w = sh[(tok0 + 3) * 130 + d2];
        const int gtok = m0 + tok0;
        const int kt = (gtok & 4095) >> 5;
        *(ushort4*)(Vimg + (size_t)(bb * 128 + kt) * VIMG_STRIDE + d * 40 + (tok0 & 31)) = v;
      }
    }
  }
}

// ---------------------------------------------------------------------------
// bf16 MFMA GEMM, bf16 in / bf16 out, leaky-relu (R9). C = act(A @ Bt^T).
// 128x128 tile, 4 waves, 2x2 MFMA subtiles/wave, pipelined K-loop, 3 blk/CU.
// ---------------------------------------------------------------------------
__global__ __launch_bounds__(256, 3) void gemm_ffn_kernel(
    const unsigned short* __restrict__ A, const unsigned short* __restrict__ Bt,
    unsigned short* __restrict__ C, int M, int N, int K)
{
  __shared__ __align__(16) unsigned short As[128 * 72];
  __shared__ __align__(16) unsigned short Bs[128 * 72];

  const int tid = threadIdx.x;
  const int w   = tid >> 6;
  const int wm  = w >> 1, wn = w & 1;
  const int l   = tid & 63;
  const int lm  = l & 31;
  const int lh  = l >> 5;

  const int m0    = blockIdx.x * 128;
  const int nbase = blockIdx.y * 128;

  f32x16 acc00, acc01, acc10, acc11;
#pragma unroll
  for (int r = 0; r < 16; ++r) { acc00[r] = 0.f; acc01[r] = 0.f; acc10[r] = 0.f; acc11[r] = 0.f; }

  const int lr = tid >> 3;
  const int lc = (tid & 7) * 8;

  bf16x8 arb[4], brb[4];

#pragma unroll
  for (int i = 0; i < 4; ++i) {
    arb[i] = *(const bf16x8*)(A  + (size_t)(m0 + i * 32 + lr) * K + lc);
    brb[i] = *(const bf16x8*)(Bt + (size_t)(nbase + i * 32 + lr) * K + lc);
  }

  for (int k0 = 0; k0 < K; k0 += 64) {
    __syncthreads();
#pragma unroll
    for (int i = 0; i < 4; ++i) {
      *(bf16x8*)&As[(i * 32 + lr) * 72 + lc] = arb[i];
      *(bf16x8*)&Bs[(i * 32 + lr) * 72 + lc] = brb[i];
    }
    __syncthreads();

    if (k0 + 64 < K) {
      const int kn = k0 + 64;
#pragma unroll
      for (int i = 0; i < 4; ++i) {
        arb[i] = *(const bf16x8*)(A  + (size_t)(m0 + i * 32 + lr) * K + kn + lc);
        brb[i] = *(const bf16x8*)(Bt + (size_t)(nbase + i * 32 + lr) * K + kn + lc);
      }
    }

#pragma unroll
    for (int ks = 0; ks < 4; ++ks) {
      bf16x8 a0 = *(const bf16x8*)&As[(wm * 64 + lm)      * 72 + ks * 16 + lh * 8];
      bf16x8 a1 = *(const bf16x8*)&As[(wm * 64 + 32 + lm) * 72 + ks * 16 + lh * 8];
      bf16x8 b0 = *(const bf16x8*)&Bs[(wn * 64 + lm)      * 72 + ks * 16 + lh * 8];
      bf16x8 b1 = *(const bf16x8*)&Bs[(wn * 64 + 32 + lm) * 72 + ks * 16 + lh * 8];
      acc00 = __builtin_amdgcn_mfma_f32_32x32x16_bf16(a0, b0, acc00, 0, 0, 0);
      acc01 = __builtin_amdgcn_mfma_f32_32x32x16_bf16(a0, b1, acc01, 0, 0, 0);
      acc10 = __builtin_amdgcn_mfma_f32_32x32x16_bf16(a1, b0, acc10, 0, 0, 0);
      acc11 = __builtin_amdgcn_mfma_f32_32x32x16_bf16(a1, b1, acc11, 0, 0, 0);
    }
  }

  const f32x16* accs[4] = { &acc00, &acc01, &acc10, &acc11 };
#pragma unroll
  for (int am = 0; am < 2; ++am)
#pragma unroll
    for (int bn = 0; bn < 2; ++bn) {
      const f32x16& a = *accs[am * 2 + bn];
#pragma unroll
      for (int r = 0; r < 16; ++r) {
        const int m = m0 + wm * 64 + am * 32 + (r & 3) + 8 * (r >> 2) + 4 * lh;
        const int n = nbase + wn * 64 + bn * 32 + lm;
        float v = a[r];
        v = v > 0.f ? v : 0.2f * v;
        C[(size_t)m * N + n] = f2bf(v);
      }
    }
}

// Out(fp32) = 0.7f * (x1b + LN(Y)), both bf16 inputs.
__global__ __launch_bounds__(256) void ln_res_bf16x_kernel(
    const unsigned short* __restrict__ Y, const unsigned short* __restrict__ X1,
    const float* __restrict__ w, const float* __restrict__ b,
    float* __restrict__ Out)
{
  const int lane = threadIdx.x & 63;
  const size_t row = (size_t)blockIdx.x * 4 + (threadIdx.x >> 6);
  ushort4 u = *(const ushort4*)&Y[row * DEMB + lane * 4];
  float y0 = bf2f(u.x), y1 = bf2f(u.y), y2 = bf2f(u.z), y3 = bf2f(u.w);
  float s  = y0 + y1 + y2 + y3;
  float sq = y0 * y0 + y1 * y1 + y2 * y2 + y3 * y3;
#pragma unroll
  for (int o = 32; o > 0; o >>= 1) { s += __shfl_down(s, o); sq += __shfl_down(sq, o); }
  s = __shfl(s, 0); sq = __shfl(sq, 0);
  const float m  = s * (1.f / DEMB);
  const float rs = rsqrtf(sq * (1.f / DEMB) - m * m + 1e-5f);
  const float4 wv = *(const float4*)&w[lane * 4];
  const float4 bv = *(const float4*)&b[lane * 4];
  const ushort4 xu = *(const ushort4*)&X1[row * DEMB + lane * 4];
  float4 o;
  o.x = 0.7f * (bf2f(xu.x) + (y0 - m) * rs * wv.x + bv.x);
  o.y = 0.7f * (bf2f(xu.y) + (y1 - m) * rs * wv.y + bv.y);
  o.z = 0.7f * (bf2f(xu.z) + (y2 - m) * rs * wv.z + bv.z);
  o.w = 0.7f * (bf2f(xu.w) + (y3 - m) * rs * wv.w + bv.w);
  *(float4*)&Out[row * DEMB + lane * 4] = o;
}

// ---------------------------------------------------------------------------
// Split-K MFMA flash attention (unchanged from R8): fixed-offset softmax,
// 512 thr, one barrier/iter, PV lags QK by one tile, K dbuf + V tbuf DMA.
// ---------------------------------------------------------------------------
__global__ __launch_bounds__(512) void attn_split_kernel(
    const unsigned short* __restrict__ Qb, const unsigned short* __restrict__ Kimg,
    const unsigned short* __restrict__ Vimg, unsigned short* __restrict__ Opart,
    float* __restrict__ lpart)
{
  __shared__ __align__(16) unsigned short Ks[2][KIMG_STRIDE];
  __shared__ __align__(16) unsigned short Vs[3][VIMG_STRIDE];
  __shared__ __align__(16) unsigned short Pb[8 * 32 * 40];

  const int tid = threadIdx.x;
  const int w   = tid >> 6;
  const int l   = tid & 63;
  const int lm  = l & 31;
  const int lh  = l >> 5;

  const int lin = blockIdx.x;
  const int xcd = lin & 7;
  const int idx = lin >> 3;
  const int b     = xcd >> 1;
  const int split = (xcd & 1) * 2 + (idx & 1);
  const int q0    = (idx >> 1) * 256;

  const unsigned short* Qbase  = Qb + (size_t)b * TSEQ * DEMB;
  const unsigned short* Ktiles = Kimg + (size_t)(b * 128 + split * 32) * KIMG_STRIDE;
  const unsigned short* Vtiles = Vimg + (size_t)(b * 128 + split * 32) * VIMG_STRIDE;

  bf16x8 qf[16];
  {
    const unsigned short* qrow = Qbase + (size_t)(q0 + w * 32 + lm) * DEMB + lh * 8;
#pragma unroll
    for (int ks = 0; ks < 16; ++ks) qf[ks] = *(const bf16x8*)(qrow + ks * 16);
  }

  f32x16 o[8];
  float lsum[16], spv[16];
#pragma unroll
  for (int t = 0; t < 8; ++t)
#pragma unroll
    for (int r = 0; r < 16; ++r) o[t][r] = 0.f;
#pragma unroll
  for (int r = 0; r < 16; ++r) lsum[r] = 0.f;

  unsigned short* Pw = &Pb[w * 32 * 40];

#pragma unroll
  for (int i = 0; i < 3; ++i) {
    const int c = w + 8 * i;
    if (c < 17) async16(&Ks[0][c * 512], Ktiles + c * 512 + l * 8);
  }
#pragma unroll
  for (int i = 0; i < 3; ++i) {
    const int c = w + 8 * i;
    if (c < 20) async16(&Vs[0][c * 512], Vtiles + c * 512 + l * 8);
  }

  {
    __syncthreads();
#pragma unroll
    for (int i = 0; i < 3; ++i) {
      const int c = w + 8 * i;
      if (c < 17) async16(&Ks[1][c * 512], Ktiles + (size_t)KIMG_STRIDE + c * 512 + l * 8);
    }
#pragma unroll
    for (int i = 0; i < 3; ++i) {
      const int c = w + 8 * i;
      if (c < 20) async16(&Vs[1][c * 512], Vtiles + (size_t)VIMG_STRIDE + c * 512 + l * 8);
    }
    f32x16 s;
#pragma unroll
    for (int r = 0; r < 16; ++r) s[r] = 0.f;
#pragma unroll
    for (int ks = 0; ks < 16; ++ks) {
      bf16x8 kf = *(const bf16x8*)&Ks[0][lm * 264 + ks * 16 + lh * 8];
      s = __builtin_amdgcn_mfma_f32_32x32x16_bf16(qf[ks], kf, s, 0, 0, 0);
    }
#pragma unroll
    for (int r = 0; r < 16; ++r) spv[r] = s[r];
  }

  int vprev = 0, vcur = 1, vnext = 2;

  for (int st = 1; st < NT; ++st) {
    __syncthreads();

    if (st + 1 < NT) {
      const unsigned short* kn = Ktiles + (size_t)(st + 1) * KIMG_STRIDE;
      const unsigned short* vn = Vtiles + (size_t)(st + 1) * VIMG_STRIDE;
#pragma unroll
      for (int i = 0; i < 3; ++i) {
        const int c = w + 8 * i;
        if (c < 17) async16(&Ks[(st + 1) & 1][c * 512], kn + c * 512 + l * 8);
      }
#pragma unroll
      for (int i = 0; i < 3; ++i) {
        const int c = w + 8 * i;
        if (c < 20) async16(&Vs[vnext][c * 512], vn + c * 512 + l * 8);
      }
    }

#pragma unroll
    for (int r = 0; r < 16; ++r) {
      const float pv = exp2f(spv[r] * 0.09016844335f - 11.541560327f);
      lsum[r] += pv;
      const int row = (r & 3) + ((r >> 2) << 3) + (lh << 2);
      Pw[row * 40 + lm] = f2bf(pv);
    }
    {
      const unsigned short* Vp = &Vs[vprev][0];
#pragma unroll
      for (int ks = 0; ks < 2; ++ks) {
        bf16x8 pf = *(const bf16x8*)&Pw[lm * 40 + ks * 16 + lh * 8];
#pragma unroll
        for (int t = 0; t < 8; ++t) {
          bf16x8 vf = *(const bf16x8*)&Vp[(t * 32 + lm) * 40 + ks * 16 + lh * 8];
          o[t] = __builtin_amdgcn_mfma_f32_32x32x16_bf16(pf, vf, o[t], 0, 0, 0);
        }
      }
    }

    {
      f32x16 s;
#pragma unroll
      for (int r = 0; r < 16; ++r) s[r] = 0.f;
      const unsigned short* Kp = &Ks[st & 1][0];
#pragma unroll
      for (int ks = 0; ks < 16; ++ks) {
        bf16x8 kf = *(const bf16x8*)&Kp[lm * 264 + ks * 16 + lh * 8];
        s = __builtin_amdgcn_mfma_f32_32x32x16_bf16(qf[ks], kf, s, 0, 0, 0);
      }
#pragma unroll
      for (int r = 0; r < 16; ++r) spv[r] = s[r];
    }

    const int tmp = vprev; vprev = vcur; vcur = vnext; vnext = tmp;
  }

#pragma unroll
  for (int r = 0; r < 16; ++r) {
    const float pv = exp2f(spv[r] * 0.09016844335f - 11.541560327f);
    lsum[r] += pv;
    const int row = (r & 3) + ((r >> 2) << 3) + (lh << 2);
    Pw[row * 40 + lm] = f2bf(pv);
  }
  {
    const unsigned short* Vp = &Vs[vprev][0];
#pragma unroll
    for (int ks = 0; ks < 2; ++ks) {
      bf16x8 pf = *(const bf16x8*)&Pw[lm * 40 + ks * 16 + lh * 8];
#pragma unroll
      for (int t = 0; t < 8; ++t) {
        bf16x8 vf = *(const bf16x8*)&Vp[(t * 32 + lm) * 40 + ks * 16 + lh * 8];
        o[t] = __builtin_amdgcn_mfma_f32_32x32x16_bf16(pf, vf, o[t], 0, 0, 0);
      }
    }
  }

#pragma unroll
  for (int r = 0; r < 16; ++r) {
#pragma unroll
    for (int d = 1; d < 32; d <<= 1) lsum[r] += __shfl_xor(lsum[r], d, 64);
  }
  unsigned short* Ob =
      Opart + ((size_t)split * NTOK + (size_t)b * TSEQ + q0 + w * 32) * DEMB;
  float* lb = lpart + (size_t)split * NTOK + (size_t)b * TSEQ + q0 + w * 32;
#pragma unroll
  for (int r = 0; r < 16; ++r) {
    const int row = (r & 3) + ((r >> 2) << 3) + (lh << 2);
#pragma unroll
    for (int t = 0; t < 8; ++t)
      Ob[(size_t)row * DEMB + t * 32 + lm] = f2bf(o[t][r]);
    if (lm == 0) lb[row] = lsum[r];
  }
}

// ---------------------------------------------------------------------------
// Combine partials + attn LayerNorm + residual; emits ONLY bf16 x1.
// ---------------------------------------------------------------------------
__global__ __launch_bounds__(256) void combine_lnres_kernel(
    const unsigned short* __restrict__ Opart, const float* __restrict__ lpart,
    const float* __restrict__ Xin, const float* __restrict__ w,
    const float* __restrict__ b, unsigned short* __restrict__ Outb)
{
  const int lane = threadIdx.x & 63;
  const size_t row = (size_t)blockIdx.x * 4 + (threadIdx.x >> 6);
  float4 acc = make_float4(0.f, 0.f, 0.f, 0.f);
  float lt = 0.f;
#pragma unroll
  for (int p = 0; p < SPLITS; ++p) {
    const ushort4 u = *(const ushort4*)&Opart[((size_t)p * NTOK + row) * DEMB + lane * 4];
    acc.x += bf2f(u.x); acc.y += bf2f(u.y);
    acc.z += bf2f(u.z); acc.w += bf2f(u.w);
    lt += lpart[(size_t)p * NTOK + row];
  }
  const float inv = 1.f / lt;
  const float y0 = acc.x * inv, y1 = acc.y * inv, y2 = acc.z * inv, y3 = acc.w * inv;
  float s  = y0 + y1 + y2 + y3;
  float sq = y0 * y0 + y1 * y1 + y2 * y2 + y3 * y3;
#pragma unroll
  for (int o = 32; o > 0; o >>= 1) { s += __shfl_down(s, o); sq += __shfl_down(sq, o); }
  s = __shfl(s, 0); sq = __shfl(sq, 0);
  const float m  = s * (1.f / DEMB);
  const float rs = rsqrtf(sq * (1.f / DEMB) - m * m + 1e-5f);
  const float4 wv = *(const float4*)&w[lane * 4];
  const float4 bv = *(const float4*)&b[lane * 4];
  const float4 xi = *(const float4*)&Xin[row * DEMB + lane * 4];
  ushort4 ob;
  ob.x = f2bf(0.7f * (xi.x + (y0 - m) * rs * wv.x + bv.x));
  ob.y = f2bf(0.7f * (xi.y + (y1 - m) * rs * wv.y + bv.y));
  ob.z = f2bf(0.7f * (xi.z + (y2 - m) * rs * wv.z + bv.z));
  ob.w = f2bf(0.7f * (xi.w + (y3 - m) * rs * wv.w + bv.w));
  *(ushort4*)&Outb[row * DEMB + lane * 4] = ob;
}

// ---------------------------------------------------------------------------
extern "C" void kernel_launch(void* const* d_in, const int* in_sizes, int n_in,
                              void* d_out, int out_size, void* d_ws, size_t ws_size,
                              hipStream_t stream)
{
  (void)in_sizes; (void)n_in; (void)out_size; (void)ws_size;
  const float* x    = (const float*)d_in[0];
  const float* qkv  = (const float*)d_in[1];
  const float* lnqw = (const float*)d_in[2];
  const float* lnqb = (const float*)d_in[3];
  const float* lnkw = (const float*)d_in[4];
  const float* lnkb = (const float*)d_in[5];
  const float* lnaw = (const float*)d_in[6];
  const float* lnab = (const float*)d_in[7];
  const float* w1   = (const float*)d_in[8];
  const float* w2   = (const float*)d_in[9];
  const float* lnfw = (const float*)d_in[10];
  const float* lnfb = (const float*)d_in[11];
  float* out = (float*)d_out;

  // byte-offset workspace (lifetimes disjoint):
  //   Qbn[0,8) Kimg[8,17) Vimg[17,28) Opart[28,62) lpart@62
  //   x1b[0,8) (over Qbn, dead after attn)
  //   H[8,25) (over Kimg/Vimg, dead after attn)
  //   Y2b[28,37) (over Opart, dead after combine)
  //   qkvT@62.5  w1b@63  w2b@63.25
  char* W = (char*)d_ws;
  const size_t MB = 1 << 20;
  unsigned short* Qbn   = (unsigned short*)(W + 0);
  unsigned short* Kimg  = (unsigned short*)(W + 8 * MB);    // 8.9 MB
  unsigned short* Vimg  = (unsigned short*)(W + 17 * MB);   // 10.5 MB
  unsigned short* Opart = (unsigned short*)(W + 28 * MB);   // 33.5 MB
  float*          lpart = (float*)(W + 62 * MB);            // 256 KB
  unsigned short* x1b   = (unsigned short*)(W + 0);
  unsigned short* H     = (unsigned short*)(W + 8 * MB);    // 16.8 MB
  unsigned short* Y2b   = (unsigned short*)(W + 28 * MB);   // 8.4 MB
  unsigned short* qkvT  = (unsigned short*)(W + 62 * MB + 512 * 1024);  // 384 KB
  unsigned short* w1b   = (unsigned short*)(W + 63 * MB);               // 256 KB
  unsigned short* w2b   = (unsigned short*)(W + 63 * MB + 256 * 1024);  // 256 KB

  const dim3 blk(256);

  // weight prep: qkv transpose+cast + w1/w2 cast
  prep_kernel<<<dim3(128, 5), blk, 0, stream>>>(qkv, w1, w2, qkvT, w1b, w2b);

  // fused QKV projection + LN(Q/K) + V-transpose (384 blocks, 2/CU)
  qkvln_kernel<<<dim3(NTOK / 128, 3), blk, 0, stream>>>(
      x, qkvT, lnqw, lnqb, lnkw, lnkb, Qbn, Kimg, Vimg);

  // attention (split-K, PV-lags-QK pipeline) + fused combine/LN/residual
  attn_split_kernel<<<dim3(256), dim3(512), 0, stream>>>(Qbn, Kimg, Vimg, Opart, lpart);
  combine_lnres_kernel<<<NTOK / 4, blk, 0, stream>>>(Opart, lpart, x, lnaw, lnab, x1b);

  // FFN (R9 split kernels, 3 blocks/CU each)
  gemm_ffn_kernel<<<dim3(NTOK / 128, HID / 128), blk, 0, stream>>>(
      x1b, w1b, H, NTOK, HID, DEMB);
  gemm_ffn_kernel<<<dim3(NTOK / 128, DEMB / 128), blk, 0, stream>>>(
      H, w2b, Y2b, NTOK, DEMB, HID);

  // out = 0.7*(x1 + LN(y2))  (both bf16 in, fp32 out)
  ln_res_bf16x_kernel<<<NTOK / 4, blk, 0, stream>>>(Y2b, x1b, lnfw, lnfb, out);
}